// Round 14
// baseline (57.102 us; speedup 1.0000x reference)
//
#include <hip/hip_runtime.h>
#include <math.h>

#define BB   16
#define CC   4
#define HH   640
#define WW   640
#define HWSZ (HH*WW)        // 409600 pixels per image
#define KM   16             // labels 1..16; 0 = background (derived)
#define NSUM (KM*CC)        // 64 channel-sum slots per image
#define NACC (NSUM+KM)      // + 16 counts = 80 slots per image
#define SIGMA_D 3.0f

#define GXB   80            // blocks per image -> 1280 blocks total
#define GPB   (HWSZ/4/GXB)  // 1280 int4-groups per block
#define HALFG (GPB/2)       // 640 groups per wave-pair
#define NIT   (HALFG/64)    // 10 wave-iterations, compile-time constant
#define NSLICE (GXB*2)      // 160 partial slices per image (block x pair)
#define ROWS  (BB*NACC)     // 1280 partial rows
#define PART_FLOATS (ROWS*NSLICE)   // 204800 floats = 819 KB

// ---------------------------------------------------------------------------
// Kernel 1: per-(image,label) channel sums + counts.
// r12's 2x2 LABEL x PIXEL SPLIT scan with BALLOTS REMOVED (single variable
// vs r12's direct 63us seg measurement). Wave pair p=w>>1 owns pixel-half p;
// within a pair, wave owns 8 labels x all 4 channels + 8 float counts = 40
// statically-indexed accumulators (r12: VGPR=60, no spill). Each pixel
// visited by 2 waves: 262 MB lane-delivered (half of r9's 524) AND ~9us
// VALU (half of r8's channel-split 20us) -- dominates both prior scans.
// Counts via cndmask+add m (r12's ballot+popcll added ~16 issue slots/visit
// + VALU->SALU->VALU serialization -> 63us).
// Locked-in: runtime-indexed register arrays spill (r1/r2); LDS atomics
// ~224cyc/inst (r3/r4); barrier lockstep duty-cycles memory (r6); contended
// global atomics ~0.67us/K (r5-r8); threadfence fusion wrecks codegen (r10);
// 2-deep prefetch == 1-deep (r13 null). Transposed partials + f4-row
// finalize ~1-3us (r12 validated). grid = (GXB, B), block = 256.
// ---------------------------------------------------------------------------
__global__ __launch_bounds__(256) void seg_kernel(
    const float* __restrict__ pred, const int* __restrict__ labels,
    float* __restrict__ part)
{
    const int b     = blockIdx.y;
    const int t     = threadIdx.x;
    const int lane  = t & 63;
    const int w     = t >> 6;            // wave 0..3
    const int pair  = w >> 1;            // pixel half
    const int lhalf = w & 1;             // label half
    const int kb    = lhalf * 8 + 1;     // first of this wave's 8 labels

    const int4*   lab4 = (const int4*)(labels + (size_t)b * HWSZ);
    const float4* p0   = (const float4*)(pred + ((size_t)b * CC + 0) * HWSZ);
    const float4* p1   = (const float4*)(pred + ((size_t)b * CC + 1) * HWSZ);
    const float4* p2   = (const float4*)(pred + ((size_t)b * CC + 2) * HWSZ);
    const float4* p3   = (const float4*)(pred + ((size_t)b * CC + 3) * HWSZ);

    const int G0 = blockIdx.x * GPB + pair * HALFG + lane;

    float acc[8][4];                     // [label][channel], static idx only
    float cnt[8];
    #pragma unroll
    for (int kk = 0; kk < 8; ++kk) {
        cnt[kk] = 0.f;
        #pragma unroll
        for (int c = 0; c < CC; ++c) acc[kk][c] = 0.f;
    }

#define PIXEL(LB, X0, X1, X2, X3)                                   \
    {                                                               \
        const int lbv = (LB);                                       \
        _Pragma("unroll")                                           \
        for (int kk = 0; kk < 8; ++kk) {                            \
            const float m = (lbv == kb + kk) ? 1.0f : 0.0f;         \
            acc[kk][0] = fmaf(m, (X0), acc[kk][0]);                 \
            acc[kk][1] = fmaf(m, (X1), acc[kk][1]);                 \
            acc[kk][2] = fmaf(m, (X2), acc[kk][2]);                 \
            acc[kk][3] = fmaf(m, (X3), acc[kk][3]);                 \
            cnt[kk]   += m;                                         \
        }                                                           \
    }

#define COMPUTE(L, Q0, Q1, Q2, Q3)                                  \
    PIXEL((L).x, (Q0).x, (Q1).x, (Q2).x, (Q3).x);                   \
    PIXEL((L).y, (Q0).y, (Q1).y, (Q2).y, (Q3).y);                   \
    PIXEL((L).z, (Q0).z, (Q1).z, (Q2).z, (Q3).z);                   \
    PIXEL((L).w, (Q0).w, (Q1).w, (Q2).w, (Q3).w);

    // software pipeline: named A/B register stages, 1-deep prefetch.
    int4   LA = lab4[G0];
    float4 A0 = p0[G0], A1 = p1[G0], A2 = p2[G0], A3 = p3[G0];
    int4   LBv;
    float4 B0, B1, B2, B3;

    #pragma unroll
    for (int it = 0; it < (NIT - 2) / 2; ++it) {       // 4 pairs: g0..g7
        const int gB = G0 + (2 * it + 1) * 64;
        LBv = lab4[gB]; B0 = p0[gB]; B1 = p1[gB]; B2 = p2[gB]; B3 = p3[gB];
        COMPUTE(LA, A0, A1, A2, A3);
        const int gA = G0 + (2 * it + 2) * 64;
        LA = lab4[gA]; A0 = p0[gA]; A1 = p1[gA]; A2 = p2[gA]; A3 = p3[gA];
        COMPUTE(LBv, B0, B1, B2, B3);
    }
    {                                                  // tail: g8, g9
        const int gB = G0 + (NIT - 1) * 64;
        LBv = lab4[gB]; B0 = p0[gB]; B1 = p1[gB]; B2 = p2[gB]; B3 = p3[gB];
        COMPUTE(LA, A0, A1, A2, A3);
        COMPUTE(LBv, B0, B1, B2, B3);
    }
#undef PIXEL
#undef COMPUTE

    // butterfly-reduce the 40 accumulators (static indices)
    #pragma unroll
    for (int kk = 0; kk < 8; ++kk) {
        #pragma unroll
        for (int c = 0; c < CC; ++c) {
            float v = acc[kk][c];
            v += __shfl_xor(v, 1);  v += __shfl_xor(v, 2);
            v += __shfl_xor(v, 4);  v += __shfl_xor(v, 8);
            v += __shfl_xor(v, 16); v += __shfl_xor(v, 32);
            acc[kk][c] = v;
        }
        float v = cnt[kk];
        v += __shfl_xor(v, 1);  v += __shfl_xor(v, 2);
        v += __shfl_xor(v, 4);  v += __shfl_xor(v, 8);
        v += __shfl_xor(v, 16); v += __shfl_xor(v, 32);
        cnt[kk] = v;
    }

    // lane 0: 40 disjoint plain stores, transposed layout part[row][slice]
    if (lane == 0) {
        const int slice = blockIdx.x * 2 + pair;       // 0..NSLICE-1
        const size_t rb = (size_t)b * NACC;
        #pragma unroll
        for (int kk = 0; kk < 8; ++kk) {
            const int kidx = kb - 1 + kk;              // 0..15
            #pragma unroll
            for (int c = 0; c < CC; ++c)
                part[(rb + kidx * 4 + c) * NSLICE + slice] = acc[kk][c];
            part[(rb + NSUM + kidx) * NSLICE + slice] = cnt[kk];
        }
    }
}

// ---------------------------------------------------------------------------
// Kernel 2: reduce NSLICE partials per row (contiguous float4), then epilogue.
// ---------------------------------------------------------------------------
__global__ __launch_bounds__(256) void finalize_kernel(
    const float* __restrict__ part, float* __restrict__ out)
{
    __shared__ float red[ROWS];               // 1280 floats
    __shared__ float s_sumg[BB], s_P[BB], s_Kb[BB];
    const float F0 = logf(SIGMA_D * SIGMA_D + 1.0f);   // log(10)
    const int t = threadIdx.x;

    // stage 1: each thread sums whole rows (160 consecutive floats = 40 f4)
    for (int r = t; r < ROWS; r += 256) {
        const float4* pr = (const float4*)(part + (size_t)r * NSLICE);
        float4 v4 = make_float4(0.f, 0.f, 0.f, 0.f);
        #pragma unroll 8
        for (int j = 0; j < NSLICE / 4; ++j) {
            float4 x = pr[j];
            v4.x += x.x; v4.y += x.y; v4.z += x.z; v4.w += x.w;
        }
        red[r] = v4.x + v4.y + v4.z + v4.w;
    }
    __syncthreads();

    // stage 2: per-image math
    if (t < BB) {
        const float* wp = red + t * NACC;
        float cnt_sum = 0.f, sum_g = 0.f, Kb = 0.f;
        for (int k = 1; k <= KM; ++k) {
            float s0 = wp[(k-1)*4+0], s1 = wp[(k-1)*4+1];
            float s2 = wp[(k-1)*4+2], s3 = wp[(k-1)*4+3];
            float cn = wp[NSUM + (k-1)];
            float N  = sqrtf(s0*s0 + s1*s1 + s2*s2 + s3*s3);
            float r  = fmaxf(SIGMA_D - N, 0.f);
            float f  = logf(r*r + 1.0f);
            sum_g   += cn * f;
            cnt_sum += cn;
            if (cn > 0.f) Kb = (float)k;
        }
        float c0 = (float)HWSZ - cnt_sum;     // background count
        sum_g += c0 * F0;
        s_sumg[t] = sum_g;
        s_Kb[t]   = Kb;
        s_P[t]    = (Kb > 1.f) ? Kb * (Kb - 1.f) * 0.5f : 0.f;  // P_act
    }
    __syncthreads();

    // stage 3: cross-image combine
    if (t == 0) {
        double sumP = 0.0;
        for (int i = 0; i < BB; ++i) sumP += (double)s_P[i];
        double total = 0.0;
        for (int i = 0; i < BB; ++i) {
            double Kb   = (double)s_Kb[i];
            double Pact = (double)s_P[i];
            double own  = 0.0;
            if (Kb > 1.0)
                own = (Kb - 1.0) * (double)s_sumg[i]
                    + (double)HWSZ * (Pact - (Kb - 1.0)) * (double)F0;
            double other = (sumP - Pact) * (double)HWSZ * (double)F0;
            double scale = (Kb > 1.0) ? 1.0 / (Kb * (Kb - 1.0)) : Kb;
            total += scale * (own + other);
        }
        out[0] = (float)total;
    }
}

// ---------------------------------------------------------------------------
extern "C" void kernel_launch(void* const* d_in, const int* in_sizes, int n_in,
                              void* d_out, int out_size, void* d_ws, size_t ws_size,
                              hipStream_t stream)
{
    const float* pred   = (const float*)d_in[0];
    const int*   labels = (const int*)d_in[1];
    float*       out    = (float*)d_out;
    float*       part   = (float*)d_ws;       // 819 KB scratch, fully overwritten

    dim3 grid(GXB, BB);
    seg_kernel<<<grid, 256, 0, stream>>>(pred, labels, part);
    finalize_kernel<<<1, 256, 0, stream>>>(part, out);
}

// Round 15
// 55.544 us; speedup vs baseline: 1.0281x; 1.0281x over previous
//
#include <hip/hip_runtime.h>
#include <math.h>

#define BB   16
#define CC   4
#define HH   640
#define WW   640
#define HWSZ (HH*WW)        // 409600 pixels per image
#define KM   16             // labels 1..16; 0 = background (derived)
#define NSUM (KM*CC)        // 64 channel-sum slots per image
#define NACC (NSUM+KM)      // + 16 counts = 80 slots per image
#define SIGMA_D 3.0f

#define GXB   160           // blocks per image -> 2560 blocks (8 resident/CU)
#define GPB   (HWSZ/4/GXB)  // 640 int4-groups per block
#define NIT   (GPB/64)      // 10 wave-iterations, compile-time constant
#define NSLICE GXB          // one partial slice per block
#define ROWS  (BB*NACC)     // 1280 partial rows
#define PART_FLOATS (ROWS*NSLICE)   // 204800 floats = 819 KB

// ---------------------------------------------------------------------------
// Kernel 1: per-(image,label) channel sums + counts.
// r9's EXACT champion scan structure (label-split: wave w owns labels
// w*4+1..+4, 20 statically-indexed accumulators, 1-deep named A/B register
// pipeline) at 2x the block residency: GXB=160 -> 8 blocks/CU = 32 waves/CU
// (r9 ran 4 blocks/CU, occupancy capped 50%, measured 29%). Single variable:
// cross-round accounting (r9 vs r12/r14: equal per-CU VALU, fewer loads,
// yet slower) killed VALU/bytes/loads as the binding resource -- the scan is
// latency/queue-bound and residency is the untested lever.
// Locked-in: runtime-indexed register arrays spill (r1/r2); LDS atomics
// ~224cyc/inst (r3/r4); barrier lockstep duty-cycles memory (r6); contended
// global atomics ~0.67us/K (r5-r8); threadfence fusion wrecks codegen (r10);
// 2-deep prefetch null (r13); 2-visit split slower at equal VALU (r12/r14);
// ballots bloat issue (r12). Transposed partials + f4-row finalize (r12,
// ~1us). grid = (GXB, B), block = 256.
// ---------------------------------------------------------------------------
__global__ __launch_bounds__(256) void seg_kernel(
    const float* __restrict__ pred, const int* __restrict__ labels,
    float* __restrict__ part)
{
    const int b     = blockIdx.y;
    const int t     = threadIdx.x;
    const int lane  = t & 63;
    const int w     = t >> 6;            // wave 0..3
    const int kbase = w * 4 + 1;         // this wave's labels

    const int4*   lab4 = (const int4*)(labels + (size_t)b * HWSZ);
    const float4* p0   = (const float4*)(pred + ((size_t)b * CC + 0) * HWSZ);
    const float4* p1   = (const float4*)(pred + ((size_t)b * CC + 1) * HWSZ);
    const float4* p2   = (const float4*)(pred + ((size_t)b * CC + 2) * HWSZ);
    const float4* p3   = (const float4*)(pred + ((size_t)b * CC + 3) * HWSZ);

    const int G0 = blockIdx.x * GPB + lane;   // this block's group window

    float acc[4][4];                     // [label][channel], static idx only
    float cnt[4];
    #pragma unroll
    for (int kk = 0; kk < 4; ++kk) {
        cnt[kk] = 0.f;
        #pragma unroll
        for (int c = 0; c < CC; ++c) acc[kk][c] = 0.f;
    }

#define PIXEL(LB, X0, X1, X2, X3)                                   \
    {                                                               \
        const int lbv = (LB);                                       \
        _Pragma("unroll")                                           \
        for (int kk = 0; kk < 4; ++kk) {                            \
            float m = (lbv == kbase + kk) ? 1.0f : 0.0f;            \
            acc[kk][0] = fmaf(m, (X0), acc[kk][0]);                 \
            acc[kk][1] = fmaf(m, (X1), acc[kk][1]);                 \
            acc[kk][2] = fmaf(m, (X2), acc[kk][2]);                 \
            acc[kk][3] = fmaf(m, (X3), acc[kk][3]);                 \
            cnt[kk]   += m;                                         \
        }                                                           \
    }

#define COMPUTE(L, Q0, Q1, Q2, Q3)                                  \
    PIXEL((L).x, (Q0).x, (Q1).x, (Q2).x, (Q3).x);                   \
    PIXEL((L).y, (Q0).y, (Q1).y, (Q2).y, (Q3).y);                   \
    PIXEL((L).z, (Q0).z, (Q1).z, (Q2).z, (Q3).z);                   \
    PIXEL((L).w, (Q0).w, (Q1).w, (Q2).w, (Q3).w);

    // software pipeline: named A/B register stages, 1-deep prefetch.
    int4   LA = lab4[G0];
    float4 A0 = p0[G0], A1 = p1[G0], A2 = p2[G0], A3 = p3[G0];
    int4   LBv;
    float4 B0, B1, B2, B3;

    #pragma unroll
    for (int it = 0; it < (NIT - 2) / 2; ++it) {       // 4 pairs: g0..g7
        const int gB = G0 + (2 * it + 1) * 64;
        LBv = lab4[gB]; B0 = p0[gB]; B1 = p1[gB]; B2 = p2[gB]; B3 = p3[gB];
        COMPUTE(LA, A0, A1, A2, A3);
        const int gA = G0 + (2 * it + 2) * 64;
        LA = lab4[gA]; A0 = p0[gA]; A1 = p1[gA]; A2 = p2[gA]; A3 = p3[gA];
        COMPUTE(LBv, B0, B1, B2, B3);
    }
    {                                                  // tail: g8, g9
        const int gB = G0 + (NIT - 1) * 64;
        LBv = lab4[gB]; B0 = p0[gB]; B1 = p1[gB]; B2 = p2[gB]; B3 = p3[gB];
        COMPUTE(LA, A0, A1, A2, A3);
        COMPUTE(LBv, B0, B1, B2, B3);
    }
#undef PIXEL
#undef COMPUTE

    // wave butterfly reduce (static indices); lane 0 stores 20 disjoint
    // slots, transposed layout part[row*NSLICE + blockIdx.x]
    #pragma unroll
    for (int kk = 0; kk < 4; ++kk) {
        #pragma unroll
        for (int c = 0; c < CC; ++c) {
            float v = acc[kk][c];
            v += __shfl_xor(v, 1);  v += __shfl_xor(v, 2);
            v += __shfl_xor(v, 4);  v += __shfl_xor(v, 8);
            v += __shfl_xor(v, 16); v += __shfl_xor(v, 32);
            acc[kk][c] = v;
        }
        float v = cnt[kk];
        v += __shfl_xor(v, 1);  v += __shfl_xor(v, 2);
        v += __shfl_xor(v, 4);  v += __shfl_xor(v, 8);
        v += __shfl_xor(v, 16); v += __shfl_xor(v, 32);
        cnt[kk] = v;
    }

    if (lane == 0) {
        const size_t rb = (size_t)b * NACC;
        #pragma unroll
        for (int kk = 0; kk < 4; ++kk) {
            const int kidx = kbase - 1 + kk;       // 0..15, disjoint per wave
            #pragma unroll
            for (int c = 0; c < CC; ++c)
                part[(rb + kidx * 4 + c) * NSLICE + blockIdx.x] = acc[kk][c];
            part[(rb + NSUM + kidx) * NSLICE + blockIdx.x] = cnt[kk];
        }
    }
}

// ---------------------------------------------------------------------------
// Kernel 2: reduce NSLICE partials per row (contiguous float4), then epilogue.
// ---------------------------------------------------------------------------
__global__ __launch_bounds__(256) void finalize_kernel(
    const float* __restrict__ part, float* __restrict__ out)
{
    __shared__ float red[ROWS];               // 1280 floats
    __shared__ float s_sumg[BB], s_P[BB], s_Kb[BB];
    const float F0 = logf(SIGMA_D * SIGMA_D + 1.0f);   // log(10)
    const int t = threadIdx.x;

    // stage 1: each thread sums whole rows (160 consecutive floats = 40 f4)
    for (int r = t; r < ROWS; r += 256) {
        const float4* pr = (const float4*)(part + (size_t)r * NSLICE);
        float4 v4 = make_float4(0.f, 0.f, 0.f, 0.f);
        #pragma unroll 8
        for (int j = 0; j < NSLICE / 4; ++j) {
            float4 x = pr[j];
            v4.x += x.x; v4.y += x.y; v4.z += x.z; v4.w += x.w;
        }
        red[r] = v4.x + v4.y + v4.z + v4.w;
    }
    __syncthreads();

    // stage 2: per-image math
    if (t < BB) {
        const float* wp = red + t * NACC;
        float cnt_sum = 0.f, sum_g = 0.f, Kb = 0.f;
        for (int k = 1; k <= KM; ++k) {
            float s0 = wp[(k-1)*4+0], s1 = wp[(k-1)*4+1];
            float s2 = wp[(k-1)*4+2], s3 = wp[(k-1)*4+3];
            float cn = wp[NSUM + (k-1)];
            float N  = sqrtf(s0*s0 + s1*s1 + s2*s2 + s3*s3);
            float r  = fmaxf(SIGMA_D - N, 0.f);
            float f  = logf(r*r + 1.0f);
            sum_g   += cn * f;
            cnt_sum += cn;
            if (cn > 0.f) Kb = (float)k;
        }
        float c0 = (float)HWSZ - cnt_sum;     // background count
        sum_g += c0 * F0;
        s_sumg[t] = sum_g;
        s_Kb[t]   = Kb;
        s_P[t]    = (Kb > 1.f) ? Kb * (Kb - 1.f) * 0.5f : 0.f;  // P_act
    }
    __syncthreads();

    // stage 3: cross-image combine
    if (t == 0) {
        double sumP = 0.0;
        for (int i = 0; i < BB; ++i) sumP += (double)s_P[i];
        double total = 0.0;
        for (int i = 0; i < BB; ++i) {
            double Kb   = (double)s_Kb[i];
            double Pact = (double)s_P[i];
            double own  = 0.0;
            if (Kb > 1.0)
                own = (Kb - 1.0) * (double)s_sumg[i]
                    + (double)HWSZ * (Pact - (Kb - 1.0)) * (double)F0;
            double other = (sumP - Pact) * (double)HWSZ * (double)F0;
            double scale = (Kb > 1.0) ? 1.0 / (Kb * (Kb - 1.0)) : Kb;
            total += scale * (own + other);
        }
        out[0] = (float)total;
    }
}

// ---------------------------------------------------------------------------
extern "C" void kernel_launch(void* const* d_in, const int* in_sizes, int n_in,
                              void* d_out, int out_size, void* d_ws, size_t ws_size,
                              hipStream_t stream)
{
    const float* pred   = (const float*)d_in[0];
    const int*   labels = (const int*)d_in[1];
    float*       out    = (float*)d_out;
    float*       part   = (float*)d_ws;       // 819 KB scratch, fully overwritten

    dim3 grid(GXB, BB);
    seg_kernel<<<grid, 256, 0, stream>>>(pred, labels, part);
    finalize_kernel<<<1, 256, 0, stream>>>(part, out);
}

// Round 16
// 42.267 us; speedup vs baseline: 1.3510x; 1.3141x over previous
//
#include <hip/hip_runtime.h>
#include <math.h>

#define BB   16
#define CC   4
#define HH   640
#define WW   640
#define HWSZ (HH*WW)        // 409600 pixels per image
#define KM   16             // labels 1..16; 0 = background (derived)
#define NSUM (KM*CC)        // 64 channel-sum slots per image
#define NACC (NSUM+KM)      // + 16 counts = 80 slots per image
#define SIGMA_D 3.0f

#define GXB   64            // blocks per image -> 1024 blocks (4/CU) [r9 champion]
#define GPB   (HWSZ/4/GXB)  // 1600 int4-groups per block
#define NIT   (GPB/64)      // 25 wave-iterations, compile-time constant
#define NSLICE GXB          // one partial slice per block (64)
#define ROWS  (BB*NACC)     // 1280 partial rows
#define PART_FLOATS (ROWS*NSLICE)   // 81920 floats = 328 KB

// ---------------------------------------------------------------------------
// Kernel 1: per-(image,label) channel sums + counts.
// r9's champion scan VERBATIM (GXB=64: fewest/longest blocks -- r13/r15
// showed block time ~= pipeline-fill (~1.2us exposed cold-miss) + NIT*steady,
// slope ~9ns/extra-block; label-split: wave w owns labels w*4+1..+4, 20
// statically-indexed accumulators; 1-deep named A/B pipeline, VGPR 52).
// ONLY change vs r9: partials stored TRANSPOSED part[row*NSLICE+block] so
// the finalize reads contiguous f4 rows (r12/r13 validated ~1us vs r9's
// ~5-8us strided version).
// Falsified levers: occupancy 2x (r15, worse), 2-deep prefetch (r13, null),
// fewer delivered bytes via 2-visit (r12/r14, worse), channel-split VALU
// (r8), LDS atomics (r3/r4, ~224cyc/inst), LDS tile barriers (r6, lockstep
// duty-cycle), contended global atomics (r5-r8, ~0.67us/K), threadfence
// fusion (r10, codegen wreck), runtime-indexed reg arrays (r1/r2, spill).
// grid = (GXB, B), block = 256.
// ---------------------------------------------------------------------------
__global__ __launch_bounds__(256) void seg_kernel(
    const float* __restrict__ pred, const int* __restrict__ labels,
    float* __restrict__ part)
{
    const int b     = blockIdx.y;
    const int t     = threadIdx.x;
    const int lane  = t & 63;
    const int w     = t >> 6;            // wave 0..3
    const int kbase = w * 4 + 1;         // this wave's labels

    const int4*   lab4 = (const int4*)(labels + (size_t)b * HWSZ);
    const float4* p0   = (const float4*)(pred + ((size_t)b * CC + 0) * HWSZ);
    const float4* p1   = (const float4*)(pred + ((size_t)b * CC + 1) * HWSZ);
    const float4* p2   = (const float4*)(pred + ((size_t)b * CC + 2) * HWSZ);
    const float4* p3   = (const float4*)(pred + ((size_t)b * CC + 3) * HWSZ);

    const int G0 = blockIdx.x * GPB + lane;   // this block's group window

    float acc[4][4];                     // [label][channel], static idx only
    float cnt[4];
    #pragma unroll
    for (int kk = 0; kk < 4; ++kk) {
        cnt[kk] = 0.f;
        #pragma unroll
        for (int c = 0; c < CC; ++c) acc[kk][c] = 0.f;
    }

#define PIXEL(LB, X0, X1, X2, X3)                                   \
    {                                                               \
        const int lbv = (LB);                                       \
        _Pragma("unroll")                                           \
        for (int kk = 0; kk < 4; ++kk) {                            \
            float m = (lbv == kbase + kk) ? 1.0f : 0.0f;            \
            acc[kk][0] = fmaf(m, (X0), acc[kk][0]);                 \
            acc[kk][1] = fmaf(m, (X1), acc[kk][1]);                 \
            acc[kk][2] = fmaf(m, (X2), acc[kk][2]);                 \
            acc[kk][3] = fmaf(m, (X3), acc[kk][3]);                 \
            cnt[kk]   += m;                                         \
        }                                                           \
    }

#define COMPUTE(L, Q0, Q1, Q2, Q3)                                  \
    PIXEL((L).x, (Q0).x, (Q1).x, (Q2).x, (Q3).x);                   \
    PIXEL((L).y, (Q0).y, (Q1).y, (Q2).y, (Q3).y);                   \
    PIXEL((L).z, (Q0).z, (Q1).z, (Q2).z, (Q3).z);                   \
    PIXEL((L).w, (Q0).w, (Q1).w, (Q2).w, (Q3).w);

    // software pipeline: named A/B register stages, 1-deep prefetch.
    int4   LA = lab4[G0];
    float4 A0 = p0[G0], A1 = p1[G0], A2 = p2[G0], A3 = p3[G0];
    int4   LBv;
    float4 B0, B1, B2, B3;

    #pragma unroll
    for (int it = 0; it < (NIT - 1) / 2; ++it) {       // 12 double-steps
        const int gB = G0 + (2 * it + 1) * 64;
        LBv = lab4[gB]; B0 = p0[gB]; B1 = p1[gB]; B2 = p2[gB]; B3 = p3[gB];
        COMPUTE(LA, A0, A1, A2, A3);
        const int gA = G0 + (2 * it + 2) * 64;
        LA = lab4[gA]; A0 = p0[gA]; A1 = p1[gA]; A2 = p2[gA]; A3 = p3[gA];
        COMPUTE(LBv, B0, B1, B2, B3);
    }
    COMPUTE(LA, A0, A1, A2, A3);                       // iteration 24
#undef PIXEL
#undef COMPUTE

    // wave butterfly reduce (static indices); lane 0 stores 20 disjoint
    // slots, TRANSPOSED layout part[row*NSLICE + blockIdx.x]
    #pragma unroll
    for (int kk = 0; kk < 4; ++kk) {
        #pragma unroll
        for (int c = 0; c < CC; ++c) {
            float v = acc[kk][c];
            v += __shfl_xor(v, 1);  v += __shfl_xor(v, 2);
            v += __shfl_xor(v, 4);  v += __shfl_xor(v, 8);
            v += __shfl_xor(v, 16); v += __shfl_xor(v, 32);
            acc[kk][c] = v;
        }
        float v = cnt[kk];
        v += __shfl_xor(v, 1);  v += __shfl_xor(v, 2);
        v += __shfl_xor(v, 4);  v += __shfl_xor(v, 8);
        v += __shfl_xor(v, 16); v += __shfl_xor(v, 32);
        cnt[kk] = v;
    }

    if (lane == 0) {
        const size_t rb = (size_t)b * NACC;
        #pragma unroll
        for (int kk = 0; kk < 4; ++kk) {
            const int kidx = kbase - 1 + kk;       // 0..15, disjoint per wave
            #pragma unroll
            for (int c = 0; c < CC; ++c)
                part[(rb + kidx * 4 + c) * NSLICE + blockIdx.x] = acc[kk][c];
            part[(rb + NSUM + kidx) * NSLICE + blockIdx.x] = cnt[kk];
        }
    }
}

// ---------------------------------------------------------------------------
// Kernel 2: reduce NSLICE partials per row (contiguous float4), then epilogue.
// ---------------------------------------------------------------------------
__global__ __launch_bounds__(256) void finalize_kernel(
    const float* __restrict__ part, float* __restrict__ out)
{
    __shared__ float red[ROWS];               // 1280 floats
    __shared__ float s_sumg[BB], s_P[BB], s_Kb[BB];
    const float F0 = logf(SIGMA_D * SIGMA_D + 1.0f);   // log(10)
    const int t = threadIdx.x;

    // stage 1: each thread sums whole rows (64 consecutive floats = 16 f4)
    for (int r = t; r < ROWS; r += 256) {
        const float4* pr = (const float4*)(part + (size_t)r * NSLICE);
        float4 v4 = make_float4(0.f, 0.f, 0.f, 0.f);
        #pragma unroll
        for (int j = 0; j < NSLICE / 4; ++j) {
            float4 x = pr[j];
            v4.x += x.x; v4.y += x.y; v4.z += x.z; v4.w += x.w;
        }
        red[r] = v4.x + v4.y + v4.z + v4.w;
    }
    __syncthreads();

    // stage 2: per-image math
    if (t < BB) {
        const float* wp = red + t * NACC;
        float cnt_sum = 0.f, sum_g = 0.f, Kb = 0.f;
        for (int k = 1; k <= KM; ++k) {
            float s0 = wp[(k-1)*4+0], s1 = wp[(k-1)*4+1];
            float s2 = wp[(k-1)*4+2], s3 = wp[(k-1)*4+3];
            float cn = wp[NSUM + (k-1)];
            float N  = sqrtf(s0*s0 + s1*s1 + s2*s2 + s3*s3);
            float r  = fmaxf(SIGMA_D - N, 0.f);
            float f  = logf(r*r + 1.0f);
            sum_g   += cn * f;
            cnt_sum += cn;
            if (cn > 0.f) Kb = (float)k;
        }
        float c0 = (float)HWSZ - cnt_sum;     // background count
        sum_g += c0 * F0;
        s_sumg[t] = sum_g;
        s_Kb[t]   = Kb;
        s_P[t]    = (Kb > 1.f) ? Kb * (Kb - 1.f) * 0.5f : 0.f;  // P_act
    }
    __syncthreads();

    // stage 3: cross-image combine
    if (t == 0) {
        double sumP = 0.0;
        for (int i = 0; i < BB; ++i) sumP += (double)s_P[i];
        double total = 0.0;
        for (int i = 0; i < BB; ++i) {
            double Kb   = (double)s_Kb[i];
            double Pact = (double)s_P[i];
            double own  = 0.0;
            if (Kb > 1.0)
                own = (Kb - 1.0) * (double)s_sumg[i]
                    + (double)HWSZ * (Pact - (Kb - 1.0)) * (double)F0;
            double other = (sumP - Pact) * (double)HWSZ * (double)F0;
            double scale = (Kb > 1.0) ? 1.0 / (Kb * (Kb - 1.0)) : Kb;
            total += scale * (own + other);
        }
        out[0] = (float)total;
    }
}

// ---------------------------------------------------------------------------
extern "C" void kernel_launch(void* const* d_in, const int* in_sizes, int n_in,
                              void* d_out, int out_size, void* d_ws, size_t ws_size,
                              hipStream_t stream)
{
    const float* pred   = (const float*)d_in[0];
    const int*   labels = (const int*)d_in[1];
    float*       out    = (float*)d_out;
    float*       part   = (float*)d_ws;       // 328 KB scratch, fully overwritten

    dim3 grid(GXB, BB);
    seg_kernel<<<grid, 256, 0, stream>>>(pred, labels, part);
    finalize_kernel<<<1, 256, 0, stream>>>(part, out);
}

// Round 17
// 40.467 us; speedup vs baseline: 1.4111x; 1.0445x over previous
//
#include <hip/hip_runtime.h>
#include <math.h>

#define BB   16
#define CC   4
#define HH   640
#define WW   640
#define HWSZ (HH*WW)        // 409600 pixels per image
#define KM   16             // labels 1..16; 0 = background (derived)
#define NSUM (KM*CC)        // 64 channel-sum slots per image
#define NACC (NSUM+KM)      // + 16 counts = 80 slots per image
#define SIGMA_D 3.0f

#define GXB   32            // blocks per image -> 512 blocks (exactly 2/CU)
#define GPB   (HWSZ/4/GXB)  // 3200 int4-groups per block
#define NIT   (GPB/64)      // 50 wave-iterations, compile-time constant
#define NSLICE GXB          // one partial slice per block (32)
#define ROWS  (BB*NACC)     // 1280 partial rows
#define PART_FLOATS (ROWS*NSLICE)   // 40960 floats = 164 KB

// ---------------------------------------------------------------------------
// Kernel 1: per-(image,label) channel sums + counts.
// r16 champion scan (label-split: wave w owns labels w*4+1..+4, 20
// statically-indexed accumulators, 1-deep named A/B pipeline, transposed
// partial stores) at GXB=32: the DISCRIMINATING experiment between the two
// surviving models for the 40us scan floor. Fill-cost model (r15/r13/r16
// monotone: 160/100/64 blocks -> 55.5/47.9/42.3us at fixed work) predicts
// ~38-40us; unique-stream-BW model (131 MB @ ~3.3 TB/s L3 path) predicts
// flat/worse (2 waves/SIMD may expose latency). Pre-commit: flat/worse ->
// r16 is the structural ceiling.
// Falsified levers: occupancy 2x (r15), 2-deep prefetch (r13), fewer
// delivered bytes (r12/r14), channel-split (r8: VALU-busy time alone =
// 41.6us), LDS atomics (r3/r4), LDS tile barriers (r6), contended global
// atomics (r5-r8), threadfence fusion (r10), runtime-indexed reg arrays
// (r1/r2), no-redundancy 80-acc variants (spill).
// grid = (GXB, B), block = 256.
// ---------------------------------------------------------------------------
__global__ __launch_bounds__(256) void seg_kernel(
    const float* __restrict__ pred, const int* __restrict__ labels,
    float* __restrict__ part)
{
    const int b     = blockIdx.y;
    const int t     = threadIdx.x;
    const int lane  = t & 63;
    const int w     = t >> 6;            // wave 0..3
    const int kbase = w * 4 + 1;         // this wave's labels

    const int4*   lab4 = (const int4*)(labels + (size_t)b * HWSZ);
    const float4* p0   = (const float4*)(pred + ((size_t)b * CC + 0) * HWSZ);
    const float4* p1   = (const float4*)(pred + ((size_t)b * CC + 1) * HWSZ);
    const float4* p2   = (const float4*)(pred + ((size_t)b * CC + 2) * HWSZ);
    const float4* p3   = (const float4*)(pred + ((size_t)b * CC + 3) * HWSZ);

    const int G0 = blockIdx.x * GPB + lane;   // this block's group window

    float acc[4][4];                     // [label][channel], static idx only
    float cnt[4];
    #pragma unroll
    for (int kk = 0; kk < 4; ++kk) {
        cnt[kk] = 0.f;
        #pragma unroll
        for (int c = 0; c < CC; ++c) acc[kk][c] = 0.f;
    }

#define PIXEL(LB, X0, X1, X2, X3)                                   \
    {                                                               \
        const int lbv = (LB);                                       \
        _Pragma("unroll")                                           \
        for (int kk = 0; kk < 4; ++kk) {                            \
            float m = (lbv == kbase + kk) ? 1.0f : 0.0f;            \
            acc[kk][0] = fmaf(m, (X0), acc[kk][0]);                 \
            acc[kk][1] = fmaf(m, (X1), acc[kk][1]);                 \
            acc[kk][2] = fmaf(m, (X2), acc[kk][2]);                 \
            acc[kk][3] = fmaf(m, (X3), acc[kk][3]);                 \
            cnt[kk]   += m;                                         \
        }                                                           \
    }

#define COMPUTE(L, Q0, Q1, Q2, Q3)                                  \
    PIXEL((L).x, (Q0).x, (Q1).x, (Q2).x, (Q3).x);                   \
    PIXEL((L).y, (Q0).y, (Q1).y, (Q2).y, (Q3).y);                   \
    PIXEL((L).z, (Q0).z, (Q1).z, (Q2).z, (Q3).z);                   \
    PIXEL((L).w, (Q0).w, (Q1).w, (Q2).w, (Q3).w);

    // software pipeline: named A/B register stages, 1-deep prefetch.
    int4   LA = lab4[G0];
    float4 A0 = p0[G0], A1 = p1[G0], A2 = p2[G0], A3 = p3[G0];
    int4   LBv;
    float4 B0, B1, B2, B3;

    #pragma unroll
    for (int it = 0; it < (NIT - 1) / 2; ++it) {       // 24 double-steps
        const int gB = G0 + (2 * it + 1) * 64;
        LBv = lab4[gB]; B0 = p0[gB]; B1 = p1[gB]; B2 = p2[gB]; B3 = p3[gB];
        COMPUTE(LA, A0, A1, A2, A3);
        const int gA = G0 + (2 * it + 2) * 64;
        LA = lab4[gA]; A0 = p0[gA]; A1 = p1[gA]; A2 = p2[gA]; A3 = p3[gA];
        COMPUTE(LBv, B0, B1, B2, B3);
    }
    COMPUTE(LA, A0, A1, A2, A3);                       // iteration 49
#undef PIXEL
#undef COMPUTE

    // wave butterfly reduce (static indices); lane 0 stores 20 disjoint
    // slots, TRANSPOSED layout part[row*NSLICE + blockIdx.x]
    #pragma unroll
    for (int kk = 0; kk < 4; ++kk) {
        #pragma unroll
        for (int c = 0; c < CC; ++c) {
            float v = acc[kk][c];
            v += __shfl_xor(v, 1);  v += __shfl_xor(v, 2);
            v += __shfl_xor(v, 4);  v += __shfl_xor(v, 8);
            v += __shfl_xor(v, 16); v += __shfl_xor(v, 32);
            acc[kk][c] = v;
        }
        float v = cnt[kk];
        v += __shfl_xor(v, 1);  v += __shfl_xor(v, 2);
        v += __shfl_xor(v, 4);  v += __shfl_xor(v, 8);
        v += __shfl_xor(v, 16); v += __shfl_xor(v, 32);
        cnt[kk] = v;
    }

    if (lane == 0) {
        const size_t rb = (size_t)b * NACC;
        #pragma unroll
        for (int kk = 0; kk < 4; ++kk) {
            const int kidx = kbase - 1 + kk;       // 0..15, disjoint per wave
            #pragma unroll
            for (int c = 0; c < CC; ++c)
                part[(rb + kidx * 4 + c) * NSLICE + blockIdx.x] = acc[kk][c];
            part[(rb + NSUM + kidx) * NSLICE + blockIdx.x] = cnt[kk];
        }
    }
}

// ---------------------------------------------------------------------------
// Kernel 2: reduce NSLICE partials per row (contiguous float4), then epilogue.
// ---------------------------------------------------------------------------
__global__ __launch_bounds__(256) void finalize_kernel(
    const float* __restrict__ part, float* __restrict__ out)
{
    __shared__ float red[ROWS];               // 1280 floats
    __shared__ float s_sumg[BB], s_P[BB], s_Kb[BB];
    const float F0 = logf(SIGMA_D * SIGMA_D + 1.0f);   // log(10)
    const int t = threadIdx.x;

    // stage 1: each thread sums whole rows (32 consecutive floats = 8 f4)
    for (int r = t; r < ROWS; r += 256) {
        const float4* pr = (const float4*)(part + (size_t)r * NSLICE);
        float4 v4 = make_float4(0.f, 0.f, 0.f, 0.f);
        #pragma unroll
        for (int j = 0; j < NSLICE / 4; ++j) {
            float4 x = pr[j];
            v4.x += x.x; v4.y += x.y; v4.z += x.z; v4.w += x.w;
        }
        red[r] = v4.x + v4.y + v4.z + v4.w;
    }
    __syncthreads();

    // stage 2: per-image math
    if (t < BB) {
        const float* wp = red + t * NACC;
        float cnt_sum = 0.f, sum_g = 0.f, Kb = 0.f;
        for (int k = 1; k <= KM; ++k) {
            float s0 = wp[(k-1)*4+0], s1 = wp[(k-1)*4+1];
            float s2 = wp[(k-1)*4+2], s3 = wp[(k-1)*4+3];
            float cn = wp[NSUM + (k-1)];
            float N  = sqrtf(s0*s0 + s1*s1 + s2*s2 + s3*s3);
            float r  = fmaxf(SIGMA_D - N, 0.f);
            float f  = logf(r*r + 1.0f);
            sum_g   += cn * f;
            cnt_sum += cn;
            if (cn > 0.f) Kb = (float)k;
        }
        float c0 = (float)HWSZ - cnt_sum;     // background count
        sum_g += c0 * F0;
        s_sumg[t] = sum_g;
        s_Kb[t]   = Kb;
        s_P[t]    = (Kb > 1.f) ? Kb * (Kb - 1.f) * 0.5f : 0.f;  // P_act
    }
    __syncthreads();

    // stage 3: cross-image combine
    if (t == 0) {
        double sumP = 0.0;
        for (int i = 0; i < BB; ++i) sumP += (double)s_P[i];
        double total = 0.0;
        for (int i = 0; i < BB; ++i) {
            double Kb   = (double)s_Kb[i];
            double Pact = (double)s_P[i];
            double own  = 0.0;
            if (Kb > 1.0)
                own = (Kb - 1.0) * (double)s_sumg[i]
                    + (double)HWSZ * (Pact - (Kb - 1.0)) * (double)F0;
            double other = (sumP - Pact) * (double)HWSZ * (double)F0;
            double scale = (Kb > 1.0) ? 1.0 / (Kb * (Kb - 1.0)) : Kb;
            total += scale * (own + other);
        }
        out[0] = (float)total;
    }
}

// ---------------------------------------------------------------------------
extern "C" void kernel_launch(void* const* d_in, const int* in_sizes, int n_in,
                              void* d_out, int out_size, void* d_ws, size_t ws_size,
                              hipStream_t stream)
{
    const float* pred   = (const float*)d_in[0];
    const int*   labels = (const int*)d_in[1];
    float*       out    = (float*)d_out;
    float*       part   = (float*)d_ws;       // 164 KB scratch, fully overwritten

    dim3 grid(GXB, BB);
    seg_kernel<<<grid, 256, 0, stream>>>(pred, labels, part);
    finalize_kernel<<<1, 256, 0, stream>>>(part, out);
}